// Round 2
// baseline (622.143 us; speedup 1.0000x reference)
//
#include <hip/hip_runtime.h>
#include <hip/hip_bf16.h>

// B=8, S=2048, H=512. out[b,i,:] = sum_{j<i} exp(q_i.x_j) x_j / (sum_{j<i} exp(q_i.x_j) + 1e-10)
// q = X @ W^T + b.
#define BATCH 8
#define SEQ   2048
#define DIM   512

typedef __bf16 bf16x8 __attribute__((ext_vector_type(8)));
typedef float  f32x4  __attribute__((ext_vector_type(4)));

__device__ __forceinline__ ushort f2bf(float f) {
    union { float f; unsigned u; } c; c.f = f;
    unsigned u = c.u;
    u += 0x7fffu + ((u >> 16) & 1u);   // round-to-nearest-even
    return (ushort)(u >> 16);
}

// ---------------- prep: X f32 -> Xb bf16 (row-major) + Xt bf16 (transposed [b][h][s]) ---------
__global__ __launch_bounds__(256) void prep_kernel(const float* __restrict__ X,
                                                   ushort* __restrict__ Xb,
                                                   ushort* __restrict__ Xt) {
    __shared__ ushort T[32 * 33];
    int t   = threadIdx.x;
    int bid = blockIdx.x;              // 8 * 64 * 16 = 8192
    int b   = bid >> 10;
    int st  = (bid >> 4) & 63;
    int ht  = bid & 15;
    int s0 = st * 32, h0 = ht * 32;

    int r  = t >> 3;                   // 0..31 (s within tile)
    int c4 = (t & 7) * 4;              // 0..28 (h within tile)
    size_t src = ((size_t)(b * SEQ + s0 + r)) * DIM + h0 + c4;
    float4 v = *(const float4*)(X + src);
    ushort u0 = f2bf(v.x), u1 = f2bf(v.y), u2 = f2bf(v.z), u3 = f2bf(v.w);
    ushort4 uv; uv.x = u0; uv.y = u1; uv.z = u2; uv.w = u3;
    *(ushort4*)(Xb + src) = uv;
    T[(c4 + 0) * 33 + r] = u0;
    T[(c4 + 1) * 33 + r] = u1;
    T[(c4 + 2) * 33 + r] = u2;
    T[(c4 + 3) * 33 + r] = u3;
    __syncthreads();
    int hh = t >> 3;                   // 0..31 (h)
    int sc = (t & 7) * 4;              // 0..28 (s)
    ushort4 w;
    w.x = T[hh * 33 + sc + 0];
    w.y = T[hh * 33 + sc + 1];
    w.z = T[hh * 33 + sc + 2];
    w.w = T[hh * 33 + sc + 3];
    *(ushort4*)(Xt + ((size_t)(b * DIM + h0 + hh)) * SEQ + s0 + sc) = w;
}

// ---------------- wconv: W f32 -> bf16 ----------------
__global__ __launch_bounds__(256) void wconv_kernel(const float* __restrict__ W,
                                                    ushort* __restrict__ Wb) {
    int gt = blockIdx.x * 256 + threadIdx.x;   // 128 blocks, 8 elems each
    size_t base = (size_t)gt * 8;
    float4 a = *(const float4*)(W + base);
    float4 c = *(const float4*)(W + base + 4);
    ushort4 lo, hi;
    lo.x = f2bf(a.x); lo.y = f2bf(a.y); lo.z = f2bf(a.z); lo.w = f2bf(a.w);
    hi.x = f2bf(c.x); hi.y = f2bf(c.y); hi.z = f2bf(c.z); hi.w = f2bf(c.w);
    *(ushort4*)(Wb + base)     = lo;
    *(ushort4*)(Wb + base + 4) = hi;
}

// ---------------- qgemm: Qb = bf16(Xb @ Wb^T + bias) ----------------
// M=B*S=16384, N=512, K=512. 128x128 tile, 4 waves (each 64x64), K-step 32.
__global__ __launch_bounds__(256, 2) void qgemm_kernel(const ushort* __restrict__ Xb,
                                                       const ushort* __restrict__ Wb,
                                                       const float* __restrict__ bias,
                                                       ushort* __restrict__ Qb) {
    __shared__ ushort At[128 * 40];
    __shared__ ushort Bt[128 * 40];
    int t   = threadIdx.x;
    int bid = blockIdx.x;              // 128 mtiles * 4 ntiles
    int mt = bid >> 2, nt = bid & 3;
    int m0 = mt << 7, n0 = nt << 7;
    int w  = t >> 6, l = t & 63, ln = l & 15, lg = l >> 4;
    int wr = w >> 1, wc = w & 1;

    f32x4 acc[4][4] = {};
    int srow = t >> 2;                 // 0..63
    int sc8  = (t & 3) * 8;            // 0,8,16,24

    for (int ks = 0; ks < 16; ++ks) {
        uint4 va0 = *(const uint4*)(Xb + (size_t)(m0 + srow) * 512 + ks * 32 + sc8);
        uint4 va1 = *(const uint4*)(Xb + (size_t)(m0 + 64 + srow) * 512 + ks * 32 + sc8);
        uint4 vb0 = *(const uint4*)(Wb + (size_t)(n0 + srow) * 512 + ks * 32 + sc8);
        uint4 vb1 = *(const uint4*)(Wb + (size_t)(n0 + 64 + srow) * 512 + ks * 32 + sc8);
        __syncthreads();               // previous iter done reading LDS
        *(uint4*)&At[srow * 40 + sc8]        = va0;
        *(uint4*)&At[(64 + srow) * 40 + sc8] = va1;
        *(uint4*)&Bt[srow * 40 + sc8]        = vb0;
        *(uint4*)&Bt[(64 + srow) * 40 + sc8] = vb1;
        __syncthreads();
        bf16x8 af[4], bfr[4];
#pragma unroll
        for (int r = 0; r < 4; ++r)
            af[r] = *(const bf16x8*)&At[(wr * 64 + r * 16 + ln) * 40 + lg * 8];
#pragma unroll
        for (int c = 0; c < 4; ++c)
            bfr[c] = *(const bf16x8*)&Bt[(wc * 64 + c * 16 + ln) * 40 + lg * 8];
#pragma unroll
        for (int r = 0; r < 4; ++r)
#pragma unroll
            for (int c = 0; c < 4; ++c)
                acc[r][c] = __builtin_amdgcn_mfma_f32_16x16x32_bf16(af[r], bfr[c], acc[r][c], 0, 0, 0);
    }

    float bv[4];
#pragma unroll
    for (int c = 0; c < 4; ++c) bv[c] = bias[n0 + wc * 64 + c * 16 + ln];
#pragma unroll
    for (int r = 0; r < 4; ++r)
#pragma unroll
        for (int c = 0; c < 4; ++c)
#pragma unroll
            for (int q = 0; q < 4; ++q) {
                int row = m0 + wr * 64 + r * 16 + lg * 4 + q;
                int col = n0 + wc * 64 + c * 16 + ln;
                Qb[(size_t)row * 512 + col] = f2bf(acc[r][c][q] + bv[c]);
            }
}

// ---------------- attn ----------------
// 2 waves / block; block owns 32 query rows (16 per wave). j-tiles of 32.
// LDS: Xr 32x520 (row-major, QK^T B-frags), Xc 512x40 (transposed, PV B-frags), Pl per-wave P.
__global__ __launch_bounds__(128, 1) void attn_kernel(const ushort* __restrict__ Xb,
                                                      const ushort* __restrict__ Xt,
                                                      const ushort* __restrict__ Qb,
                                                      float* __restrict__ out) {
    __shared__ ushort Xr[32 * 520];
    __shared__ ushort Xc[512 * 40];
    __shared__ ushort Pl[2 * 16 * 40];

    int t   = threadIdx.x;
    int bid = blockIdx.x;              // 512 = 8 batches x 64 q-tiles
    int b   = bid & 7;                 // batch -> XCD affinity (4MB bf16 set fits one XCD L2)
    int k   = bid >> 3;                // 0..63
    int qt  = (k < 32) ? (63 - k) : (k - 32);   // stride-32-paired heavy/light order

    int w = t >> 6, l = t & 63, ln = l & 15, lg = l >> 4;
    int gi0 = b * SEQ + qt * 32 + w * 16;       // flattened global row base for this wave
    int iq  = qt * 32 + w * 16 + lg * 4;        // in-batch query row base (for mask)

    bf16x8 qf[16];
#pragma unroll
    for (int ks = 0; ks < 16; ++ks)
        qf[ks] = *(const bf16x8*)(Qb + (size_t)(gi0 + ln) * 512 + ks * 32 + lg * 8);

    f32x4 acc[32] = {};
    float den[4] = {0.f, 0.f, 0.f, 0.f};

    int srr = t >> 6;                  // Xr staging: row parity
    int sc8 = (t & 63) * 8;            // Xr staging: col chunk
    int sth = t >> 2;                  // Xc staging: h within pass (0..31)
    int stj = (t & 3) * 8;             // Xc staging: j chunk

    for (int jt = 0; jt <= qt; ++jt) {
        int j0 = jt * 32;
        __syncthreads();               // previous iter done reading LDS
#pragma unroll
        for (int p = 0; p < 16; ++p) {
            int row = p * 2 + srr;
            uint4 vr = *(const uint4*)(Xb + (size_t)(b * SEQ + j0 + row) * 512 + sc8);
            *(uint4*)&Xr[row * 520 + sc8] = vr;
            int h = p * 32 + sth;
            uint4 vc = *(const uint4*)(Xt + (size_t)(b * DIM + h) * SEQ + j0 + stj);
            *(uint4*)&Xc[h * 40 + stj] = vc;
        }
        __syncthreads();

        // QK^T: S[16 x 32] over K=512
        f32x4 s0v = {}, s1v = {};
#pragma unroll
        for (int ks = 0; ks < 16; ++ks) {
            bf16x8 b0 = *(const bf16x8*)&Xr[ln * 520 + ks * 32 + lg * 8];
            bf16x8 b1 = *(const bf16x8*)&Xr[(16 + ln) * 520 + ks * 32 + lg * 8];
            s0v = __builtin_amdgcn_mfma_f32_16x16x32_bf16(qf[ks], b0, s0v, 0, 0, 0);
            s1v = __builtin_amdgcn_mfma_f32_16x16x32_bf16(qf[ks], b1, s1v, 0, 0, 0);
        }

        // exp + strict-causal mask + denom rowsum + P -> LDS (bf16)
#pragma unroll
        for (int r = 0; r < 4; ++r) {
            int gi = iq + r;
            float p0 = ((j0 + ln) < gi)      ? __expf(s0v[r]) : 0.f;
            float p1 = ((j0 + 16 + ln) < gi) ? __expf(s1v[r]) : 0.f;
            float tr = p0 + p1;
            tr += __shfl_xor(tr, 1);
            tr += __shfl_xor(tr, 2);
            tr += __shfl_xor(tr, 4);
            tr += __shfl_xor(tr, 8);
            den[r] += tr;
            Pl[(w * 16 + lg * 4 + r) * 40 + ln]      = f2bf(p0);
            Pl[(w * 16 + lg * 4 + r) * 40 + 16 + ln] = f2bf(p1);
        }

        // PV: O[16 x 512] += P[16 x 32] @ X_j[32 x 512]
        bf16x8 pa = *(const bf16x8*)&Pl[(w * 16 + ln) * 40 + lg * 8];
#pragma unroll
        for (int cf = 0; cf < 32; ++cf) {
            bf16x8 bv = *(const bf16x8*)&Xc[(cf * 16 + ln) * 40 + lg * 8];
            acc[cf] = __builtin_amdgcn_mfma_f32_16x16x32_bf16(pa, bv, acc[cf], 0, 0, 0);
        }
    }

    // epilogue: out = acc / (den + 1e-10)
#pragma unroll
    for (int r = 0; r < 4; ++r) {
        float inv = 1.0f / (den[r] + 1e-10f);
#pragma unroll
        for (int cf = 0; cf < 32; ++cf) {
            out[(size_t)(gi0 + lg * 4 + r) * 512 + cf * 16 + ln] = acc[cf][r] * inv;
        }
    }
}

extern "C" void kernel_launch(void* const* d_in, const int* in_sizes, int n_in,
                              void* d_out, int out_size, void* d_ws, size_t ws_size,
                              hipStream_t stream) {
    const float* X    = (const float*)d_in[0];
    const float* W    = (const float*)d_in[1];
    const float* bias = (const float*)d_in[2];
    float* out = (float*)d_out;

    // ws layout (ushort elems): Xb[8.4M] | Xt[8.4M] | Qb[8.4M] | Wb[256K]  (~48.5 MB total)
    ushort* ws = (ushort*)d_ws;
    ushort* Xb = ws;
    ushort* Xt = ws + 8388608;
    ushort* Qb = ws + 16777216;
    ushort* Wb = ws + 25165824;

    prep_kernel<<<dim3(8192), dim3(256), 0, stream>>>(X, Xb, Xt);
    wconv_kernel<<<dim3(128), dim3(256), 0, stream>>>(W, Wb);
    qgemm_kernel<<<dim3(512), dim3(256), 0, stream>>>(Xb, Wb, bias, Qb);
    attn_kernel<<<dim3(512), dim3(128), 0, stream>>>(Xb, Xt, Qb, out);
}

// Round 3
// 336.258 us; speedup vs baseline: 1.8502x; 1.8502x over previous
//
#include <hip/hip_runtime.h>
#include <hip/hip_bf16.h>

// B=8, S=2048, H=512. out[b,i,:] = sum_{j<i} exp(q_i.x_j) x_j / (sum_{j<i} exp(q_i.x_j) + 1e-10)
// q = X @ W^T + b.  No softmax max-subtract => j-partial sums are ADDITIVE => split-j blocks + atomics.
#define BATCH 8
#define SEQ   2048
#define DIM   512

typedef __bf16 bf16x8 __attribute__((ext_vector_type(8)));
typedef float  f32x4  __attribute__((ext_vector_type(4)));

__device__ __forceinline__ ushort f2bf(float f) {
    union { float f; unsigned u; } c; c.f = f;
    unsigned u = c.u;
    u += 0x7fffu + ((u >> 16) & 1u);   // round-to-nearest-even
    return (ushort)(u >> 16);
}

// ---------------- prep: X f32 -> Xb bf16 (row-major) + Xt bf16 (transposed [b][h][s]) ---------
__global__ __launch_bounds__(256) void prep_kernel(const float* __restrict__ X,
                                                   ushort* __restrict__ Xb,
                                                   ushort* __restrict__ Xt) {
    __shared__ ushort T[32 * 33];
    int t   = threadIdx.x;
    int bid = blockIdx.x;              // 8 * 64 * 16 = 8192
    int b   = bid >> 10;
    int st  = (bid >> 4) & 63;
    int ht  = bid & 15;
    int s0 = st * 32, h0 = ht * 32;

    int r  = t >> 3;                   // 0..31 (s within tile)
    int c4 = (t & 7) * 4;              // 0..28 (h within tile)
    size_t src = ((size_t)(b * SEQ + s0 + r)) * DIM + h0 + c4;
    float4 v = *(const float4*)(X + src);
    ushort u0 = f2bf(v.x), u1 = f2bf(v.y), u2 = f2bf(v.z), u3 = f2bf(v.w);
    ushort4 uv; uv.x = u0; uv.y = u1; uv.z = u2; uv.w = u3;
    *(ushort4*)(Xb + src) = uv;
    T[(c4 + 0) * 33 + r] = u0;
    T[(c4 + 1) * 33 + r] = u1;
    T[(c4 + 2) * 33 + r] = u2;
    T[(c4 + 3) * 33 + r] = u3;
    __syncthreads();
    int hh = t >> 3;                   // 0..31 (h)
    int sc = (t & 7) * 4;              // 0..28 (s)
    ushort4 w;
    w.x = T[hh * 33 + sc + 0];
    w.y = T[hh * 33 + sc + 1];
    w.z = T[hh * 33 + sc + 2];
    w.w = T[hh * 33 + sc + 3];
    *(ushort4*)(Xt + ((size_t)(b * DIM + h0 + hh)) * SEQ + s0 + sc) = w;
}

// ---------------- wconv: W f32 -> bf16 ----------------
__global__ __launch_bounds__(256) void wconv_kernel(const float* __restrict__ W,
                                                    ushort* __restrict__ Wb) {
    int gt = blockIdx.x * 256 + threadIdx.x;   // 128 blocks, 8 elems each
    size_t base = (size_t)gt * 8;
    float4 a = *(const float4*)(W + base);
    float4 c = *(const float4*)(W + base + 4);
    ushort4 lo, hi;
    lo.x = f2bf(a.x); lo.y = f2bf(a.y); lo.z = f2bf(a.z); lo.w = f2bf(a.w);
    hi.x = f2bf(c.x); hi.y = f2bf(c.y); hi.z = f2bf(c.z); hi.w = f2bf(c.w);
    *(ushort4*)(Wb + base)     = lo;
    *(ushort4*)(Wb + base + 4) = hi;
}

// ---------------- qgemm: Qb = bf16(Xb @ Wb^T + bias) ----------------
// M=B*S=16384, N=512, K=512. 128x128 tile, 4 waves (each 64x64), K-step 32.
__global__ __launch_bounds__(256, 2) void qgemm_kernel(const ushort* __restrict__ Xb,
                                                       const ushort* __restrict__ Wb,
                                                       const float* __restrict__ bias,
                                                       ushort* __restrict__ Qb) {
    __shared__ ushort At[128 * 40];
    __shared__ ushort Bt[128 * 40];
    int t   = threadIdx.x;
    int bid = blockIdx.x;              // 128 mtiles * 4 ntiles
    int mt = bid >> 2, nt = bid & 3;
    int m0 = mt << 7, n0 = nt << 7;
    int w  = t >> 6, l = t & 63, ln = l & 15, lg = l >> 4;
    int wr = w >> 1, wc = w & 1;

    f32x4 acc[4][4] = {};
    int srow = t >> 2;                 // 0..63
    int sc8  = (t & 3) * 8;            // 0,8,16,24

    for (int ks = 0; ks < 16; ++ks) {
        uint4 va0 = *(const uint4*)(Xb + (size_t)(m0 + srow) * 512 + ks * 32 + sc8);
        uint4 va1 = *(const uint4*)(Xb + (size_t)(m0 + 64 + srow) * 512 + ks * 32 + sc8);
        uint4 vb0 = *(const uint4*)(Wb + (size_t)(n0 + srow) * 512 + ks * 32 + sc8);
        uint4 vb1 = *(const uint4*)(Wb + (size_t)(n0 + 64 + srow) * 512 + ks * 32 + sc8);
        __syncthreads();               // previous iter done reading LDS
        *(uint4*)&At[srow * 40 + sc8]        = va0;
        *(uint4*)&At[(64 + srow) * 40 + sc8] = va1;
        *(uint4*)&Bt[srow * 40 + sc8]        = vb0;
        *(uint4*)&Bt[(64 + srow) * 40 + sc8] = vb1;
        __syncthreads();
        bf16x8 af[4], bfr[4];
#pragma unroll
        for (int r = 0; r < 4; ++r)
            af[r] = *(const bf16x8*)&At[(wr * 64 + r * 16 + ln) * 40 + lg * 8];
#pragma unroll
        for (int c = 0; c < 4; ++c)
            bfr[c] = *(const bf16x8*)&Bt[(wc * 64 + c * 16 + ln) * 40 + lg * 8];
#pragma unroll
        for (int r = 0; r < 4; ++r)
#pragma unroll
            for (int c = 0; c < 4; ++c)
                acc[r][c] = __builtin_amdgcn_mfma_f32_16x16x32_bf16(af[r], bfr[c], acc[r][c], 0, 0, 0);
    }

    float bv[4];
#pragma unroll
    for (int c = 0; c < 4; ++c) bv[c] = bias[n0 + wc * 64 + c * 16 + ln];
#pragma unroll
    for (int r = 0; r < 4; ++r)
#pragma unroll
        for (int c = 0; c < 4; ++c)
#pragma unroll
            for (int q = 0; q < 4; ++q) {
                int row = m0 + wr * 64 + r * 16 + lg * 4 + q;
                int col = n0 + wc * 64 + c * 16 + ln;
                Qb[(size_t)row * 512 + col] = f2bf(acc[r][c][q] + bv[c]);
            }
}

// ---------------- attn2: split-j, 4 waves, q-tile 64, atomically accumulate num/den -----------
// Work item: (batch b, q64-tile qt, chunk of <=8 j32-subtiles). nsub(qt)=2qt+2, nchunk=(2qt+9)>>3.
// Grid = 8 * 144 = 1152 blocks, heavy chunks launched first.
__global__ __launch_bounds__(256, 2) void attn2_kernel(const ushort* __restrict__ Xb,
                                                       const ushort* __restrict__ Xt,
                                                       const ushort* __restrict__ Qb,
                                                       float* __restrict__ num,
                                                       float* __restrict__ den) {
    __shared__ ushort Xr[32 * 520];        // X rows j0..j0+31 (QK^T B-frags)
    __shared__ ushort Xc[512 * 40];        // X^T cols (PV B-frags)
    __shared__ ushort Pl[4 * 16 * 40];     // per-wave P fixup buffer

    int t   = threadIdx.x;
    int bid = blockIdx.x;
    int b   = bid & 7;                     // batch -> XCD affinity
    int c   = 143 - (bid >> 3);            // heavy chunks (large qt) first

    int qt = 0, base = 0;
    for (qt = 0; qt < 32; ++qt) {          // uniform scalar loop, negligible
        int nc = (2 * qt + 9) >> 3;
        if (c < base + nc) break;
        base += nc;
    }
    int ci  = c - base;
    int js0 = ci * 8;
    int js1 = min(js0 + 8, 2 * qt + 2);

    int w = t >> 6, l = t & 63, ln = l & 15, lg = l >> 4;
    int r0  = qt * 64 + w * 16;            // wave's first query row (in batch)
    int gi0 = b * SEQ + r0;                // flattened

    bf16x8 qf[16];
#pragma unroll
    for (int ks = 0; ks < 16; ++ks)
        qf[ks] = *(const bf16x8*)(Qb + (size_t)(gi0 + ln) * 512 + ks * 32 + lg * 8);

    f32x4 acc[32] = {};
    float dacc[4] = {0.f, 0.f, 0.f, 0.f};
    bool touched = false;

    int xr_row = t >> 6;                   // + p*4
    int xr_c8  = (t & 63) * 8;
    int xc_h   = t >> 2;                   // + p*64
    int xc_j8  = (t & 3) * 8;

    for (int js = js0; js < js1; ++js) {
        int j0 = js * 32;
        uint4 vr[8];
#pragma unroll
        for (int p = 0; p < 8; ++p)
            vr[p] = *(const uint4*)(Xb + (size_t)(b * SEQ + j0 + p * 4 + xr_row) * 512 + xr_c8);
        __syncthreads();                   // previous iter done reading LDS
#pragma unroll
        for (int p = 0; p < 8; ++p)
            *(uint4*)&Xr[(p * 4 + xr_row) * 520 + xr_c8] = vr[p];
        uint4 vc[8];
#pragma unroll
        for (int p = 0; p < 8; ++p)
            vc[p] = *(const uint4*)(Xt + (size_t)(b * DIM + p * 64 + xc_h) * SEQ + j0 + xc_j8);
#pragma unroll
        for (int p = 0; p < 8; ++p)
            *(uint4*)&Xc[(p * 64 + xc_h) * 40 + xc_j8] = vc[p];
        __syncthreads();

        if (j0 < r0 + 15) {                // wave has at least one unmasked (j<i) element
            touched = true;
            f32x4 s0v = {}, s1v = {};
#pragma unroll
            for (int ks = 0; ks < 16; ++ks) {
                bf16x8 b0 = *(const bf16x8*)&Xr[ln * 520 + ks * 32 + lg * 8];
                bf16x8 b1 = *(const bf16x8*)&Xr[(16 + ln) * 520 + ks * 32 + lg * 8];
                s0v = __builtin_amdgcn_mfma_f32_16x16x32_bf16(qf[ks], b0, s0v, 0, 0, 0);
                s1v = __builtin_amdgcn_mfma_f32_16x16x32_bf16(qf[ks], b1, s1v, 0, 0, 0);
            }
#pragma unroll
            for (int r = 0; r < 4; ++r) {
                int gi = r0 + lg * 4 + r;
                float p0 = ((j0 + ln) < gi)      ? __expf(s0v[r]) : 0.f;
                float p1 = ((j0 + 16 + ln) < gi) ? __expf(s1v[r]) : 0.f;
                float tr = p0 + p1;
                tr += __shfl_xor(tr, 1);
                tr += __shfl_xor(tr, 2);
                tr += __shfl_xor(tr, 4);
                tr += __shfl_xor(tr, 8);
                dacc[r] += tr;
                Pl[(w * 16 + lg * 4 + r) * 40 + ln]      = f2bf(p0);
                Pl[(w * 16 + lg * 4 + r) * 40 + 16 + ln] = f2bf(p1);
            }
            bf16x8 pa = *(const bf16x8*)&Pl[(w * 16 + ln) * 40 + lg * 8];
#pragma unroll
            for (int cf = 0; cf < 32; ++cf) {
                bf16x8 bv = *(const bf16x8*)&Xc[(cf * 16 + ln) * 40 + lg * 8];
                acc[cf] = __builtin_amdgcn_mfma_f32_16x16x32_bf16(pa, bv, acc[cf], 0, 0, 0);
            }
        }
    }

    if (touched) {
#pragma unroll
        for (int r = 0; r < 4; ++r) {
            size_t row = (size_t)(gi0 + lg * 4 + r) * 512;
#pragma unroll
            for (int cf = 0; cf < 32; ++cf)
                unsafeAtomicAdd(&num[row + cf * 16 + ln], acc[cf][r]);
        }
        if (ln == 0) {
#pragma unroll
            for (int r = 0; r < 4; ++r)
                unsafeAtomicAdd(&den[gi0 + lg * 4 + r], dacc[r]);
        }
    }
}

// ---------------- divide: out = num / (den + 1e-10) ----------------
__global__ __launch_bounds__(256) void divide_kernel(float* __restrict__ num,
                                                     const float* __restrict__ den) {
    int idx = blockIdx.x * 256 + threadIdx.x;      // 8192 blocks -> 2,097,152 float4
    float4 v = ((const float4*)num)[idx];
    int row = idx >> 7;                            // 128 float4 per 512-col row
    float inv = 1.0f / (den[row] + 1e-10f);
    v.x *= inv; v.y *= inv; v.z *= inv; v.w *= inv;
    ((float4*)num)[idx] = v;
}

extern "C" void kernel_launch(void* const* d_in, const int* in_sizes, int n_in,
                              void* d_out, int out_size, void* d_ws, size_t ws_size,
                              hipStream_t stream) {
    const float* X    = (const float*)d_in[0];
    const float* W    = (const float*)d_in[1];
    const float* bias = (const float*)d_in[2];
    float* out = (float*)d_out;

    // ws layout (bytes): Xb[16.78M] | Xt[16.78M] | Qb[16.78M] | Wb[512K] | den[64K]
    ushort* ws = (ushort*)d_ws;
    ushort* Xb = ws;
    ushort* Xt = ws + 8388608;
    ushort* Qb = ws + 16777216;
    ushort* Wb = ws + 25165824;
    float*  den = (float*)((char*)d_ws + 50855936);

    hipMemsetAsync(out, 0, (size_t)BATCH * SEQ * DIM * sizeof(float), stream);
    hipMemsetAsync(den, 0, (size_t)BATCH * SEQ * sizeof(float), stream);

    prep_kernel<<<dim3(8192), dim3(256), 0, stream>>>(X, Xb, Xt);
    wconv_kernel<<<dim3(128), dim3(256), 0, stream>>>(W, Wb);
    qgemm_kernel<<<dim3(512), dim3(256), 0, stream>>>(Xb, Wb, bias, Qb);
    attn2_kernel<<<dim3(1152), dim3(256), 0, stream>>>(Xb, Xt, Qb, out, den);
    divide_kernel<<<dim3(8192), dim3(256), 0, stream>>>(out, den);
}